// Round 17
// baseline (166.485 us; speedup 1.0000x reference)
//
#include <hip/hip_runtime.h>
#include <hip/hip_bf16.h>
#include <cstddef>
#include <cstdint>

// Problem constants
#define B   32
#define C   16
#define H   64
#define D   256
#define K   2048
#define T   15
#define PAD 7
#define EPS 1e-5

#define BH      (B*H)       // 2048
#define ROWS    (B*C*H)     // 32768 VQ rows
#define N_PER_CH ((double)(B*H*D)) // 524288
#define NC  8               // candidates per row (4 per N-half)

typedef __attribute__((ext_vector_type(8))) short bf16x8;
typedef __attribute__((ext_vector_type(4))) float f32x4;

__device__ __forceinline__ void gload_lds16(const void* g, void* l) {
  __builtin_amdgcn_global_load_lds(
      (const __attribute__((address_space(1))) unsigned int*)g,
      (__attribute__((address_space(3))) unsigned int*)l, 16, 0, 0);
}

// ---------------------------------------------------------------------------
// K0 (fused): blocks [0,BH): stats-only encoder conv (f64) partial sums
//             (transposed partial layout [c][bh] for coalesced k2 reads).
//             blocks [BH, BH+512): emb prep — enorm f64 (+f32) + bf16 cast.
// ---------------------------------------------------------------------------
__global__ __launch_bounds__(256) void k0_fused(
    const float* __restrict__ x, const float* __restrict__ w,
    double* __restrict__ partial /* [C][BH][2] */,
    const float* __restrict__ emb, double* __restrict__ enorm,
    float* __restrict__ enormf, __hip_bfloat16* __restrict__ embB) {
  __shared__ __attribute__((aligned(16))) float xs[272];
  __shared__ float wsm[C*T];
  const int bh = blockIdx.x, tid = threadIdx.x;
  if (bh >= BH) {
    const int k = (bh - BH) * 4 + (tid >> 6);
    const int lane = tid & 63;
    const float4 ev = *(const float4*)(emb + ((size_t)k << 8) + lane*4);
    __hip_bfloat16 hb[4] = {__float2bfloat16(ev.x), __float2bfloat16(ev.y),
                            __float2bfloat16(ev.z), __float2bfloat16(ev.w)};
    *(int2*)(embB + ((size_t)k << 8) + lane*4) = *(const int2*)hb;
    double s = fma((double)ev.x, (double)ev.x,
               fma((double)ev.y, (double)ev.y,
               fma((double)ev.z, (double)ev.z,
                   (double)ev.w * (double)ev.w)));
#pragma unroll
    for (int off = 1; off < 64; off <<= 1) s += __shfl_xor(s, off, 64);
    if (lane == 0) { enorm[k] = s; enormf[k] = (float)s; }
    return;
  }
  const float* xrow = x + ((size_t)bh << 8);
  if (tid < C*T) wsm[tid] = w[tid];
  xs[tid] = (tid >= 7 && tid < 263) ? xrow[tid - 7] : 0.f;
  if (tid < 16) { int i = 256 + tid; xs[i] = (i < 263) ? xrow[i - 7] : 0.f; }
  __syncthreads();
  const int c = tid >> 4, s = tid & 15;
  float xr[32];
#pragma unroll
  for (int kq = 0; kq < 8; kq++)
    *(float4*)&xr[kq*4] = *(const float4*)&xs[s*16 + kq*4];
  float wv[T];
#pragma unroll
  for (int t = 0; t < T; t++) wv[t] = wsm[c*T + t];
  double sum = 0.0, sq = 0.0;
#pragma unroll
  for (int d0 = 0; d0 < 16; d0++) {
    double z = 0.0;
#pragma unroll
    for (int t = 0; t < T; t++) z = fma((double)wv[t], (double)xr[d0 + t], z);
    sum += z; sq = fma(z, z, sq);
  }
#pragma unroll
  for (int off = 1; off < 16; off <<= 1) {
    sum += __shfl_xor(sum, off, 64);
    sq  += __shfl_xor(sq,  off, 64);
  }
  if (s == 0) {
    partial[((size_t)c*BH + bh)*2 + 0] = sum;
    partial[((size_t)c*BH + bh)*2 + 1] = sq;
  }
}

// ---------------------------------------------------------------------------
// K2: finalize BN per-channel params (deterministic tree, coalesced reads)
// ---------------------------------------------------------------------------
__global__ __launch_bounds__(256) void k2_stats_final(
    const double* __restrict__ partial, const float* __restrict__ gamma,
    const float* __restrict__ beta, double* __restrict__ params) {
  __shared__ double rs[256], rq[256];
  const int c = blockIdx.x;
  const int tid = threadIdx.x;
  double s = 0.0, q = 0.0;
  for (int i = tid; i < BH; i += 256) {
    s += partial[((size_t)c*BH + i)*2 + 0];
    q += partial[((size_t)c*BH + i)*2 + 1];
  }
  rs[tid] = s; rq[tid] = q;
  __syncthreads();
  for (int off = 128; off; off >>= 1) {
    if (tid < off) { rs[tid] += rs[tid + off]; rq[tid] += rq[tid + off]; }
    __syncthreads();
  }
  if (tid == 0) {
    double m = rs[0] / N_PER_CH;
    double v = rq[0] / N_PER_CH - m * m;
    double a = (double)gamma[c] / sqrt(v + EPS);
    double b = (double)beta[c] - a * m;
    params[c*4+0] = m; params[c*4+1] = v; params[c*4+2] = a; params[c*4+3] = b;
  }
}

// ---------------------------------------------------------------------------
// K1b: encoder conv (f64) + fused affine -> z_e f32 (output) + z_e bf16 (k4 A)
// ---------------------------------------------------------------------------
__global__ __launch_bounds__(256) void k1b_ze(
    const float* __restrict__ x, const float* __restrict__ w,
    const double* __restrict__ params, float* __restrict__ zE,
    __hip_bfloat16* __restrict__ zEb) {
  __shared__ __attribute__((aligned(16))) float xs[272];
  __shared__ float wsm[C*T];
  const int bh = blockIdx.x, tid = threadIdx.x;
  const int b = bh >> 6, h = bh & 63;
  const float* xrow = x + ((size_t)bh << 8);
  if (tid < C*T) wsm[tid] = w[tid];
  xs[tid] = (tid >= 7 && tid < 263) ? xrow[tid - 7] : 0.f;
  if (tid < 16) { int i = 256 + tid; xs[i] = (i < 263) ? xrow[i - 7] : 0.f; }
  __syncthreads();
  const int c = tid >> 4, s = tid & 15;
  float xr[32];
#pragma unroll
  for (int kq = 0; kq < 8; kq++)
    *(float4*)&xr[kq*4] = *(const float4*)&xs[s*16 + kq*4];
  float wv[T];
#pragma unroll
  for (int t = 0; t < T; t++) wv[t] = wsm[c*T + t];
  const double a = params[c*4+2], bb = params[c*4+3];
  float zf[16];
  __hip_bfloat16 zb[16];
#pragma unroll
  for (int d0 = 0; d0 < 16; d0++) {
    double z = 0.0;
#pragma unroll
    for (int t = 0; t < T; t++) z = fma((double)wv[t], (double)xr[d0 + t], z);
    double ze = fma(a, z, bb);
    zf[d0] = (float)ze;
    zb[d0] = __float2bfloat16(zf[d0]);
  }
  const size_t rbase = ((((size_t)b*C + c)*H + h) << 8) + s*16;
#pragma unroll
  for (int kq = 0; kq < 4; kq++)
    *(float4*)(zE + rbase + kq*4) = *(const float4*)&zf[kq*4];
  *(int4*)(zEb + rbase)     = *(const int4*)&zb[0];
  *(int4*)(zEb + rbase + 8) = *(const int4*)&zb[8];
}

// ---------------------------------------------------------------------------
// K4: r13/r16 structure + OWN-STAGING single-barrier step:
// each wave stages exactly the 4 B-frags it reads (wr-partner duplicates,
// identical bytes). Step = {lgkm(0)+barrier (slot-reuse safety); stage(t+1);
// exact vmcnt(4/8) for own stage(t); [kk==0: en prefetch]; ds_read; MFMA;
// [dp epilogue]}. Exact counts: queue = [st(t):4, (en:4 iff kk==1), st(t+1):4].
// ---------------------------------------------------------------------------
__global__ __launch_bounds__(256, 2) void k4_mfma(
    const __hip_bfloat16* __restrict__ zEb, const __hip_bfloat16* __restrict__ embB,
    const float* __restrict__ enormf, int* __restrict__ cand /*[ROWS][NC]*/) {
  __shared__ __attribute__((aligned(16))) __hip_bfloat16 Ash[64][512];   // 64 KB
  __shared__ __attribute__((aligned(16))) __hip_bfloat16 Bsh[2][8][512]; // 16 KB

  const int tid  = threadIdx.x;
  const int w    = tid >> 6, lane = tid & 63;
  const int wr   = w >> 1,   wc   = w & 1;
  const int l15  = lane & 15, l4  = lane >> 4;
  const int mblk = blockIdx.x >> 1, nhalf = blockIdx.x & 1;
  const int row0 = mblk * 128;
  const int n0   = nhalf * 1024;

  // ---- prologue: A slab (16 frags/wave) + OWN stage step 0 ----
#pragma unroll
  for (int i = 0; i < 16; i++) {
    int f = w*16 + i;
    int kk = f >> 3, mf = f & 7;
    gload_lds16(zEb + (((size_t)(row0 + mf*16 + l15)) << 8) + kk*32 + l4*8,
                &Ash[kk*8 + mf][0]);
  }
  auto stageB = [&](int t) {     // stage THIS WAVE'S 4 frags (wc*4..wc*4+3)
    const int slot = t & 1, nt = t >> 3, kk = t & 7;
#pragma unroll
    for (int n = 0; n < 4; n++) {
      const int nf = wc*4 + n;
      gload_lds16(embB + (((size_t)(n0 + nt*128 + nf*16 + l15)) << 8) + kk*32 + l4*8,
                  &Bsh[slot][nf][0]);
    }
  };
  stageB(0);
  asm volatile("s_waitcnt vmcnt(4)" ::: "memory");   // own A landed; st0 in flight
  __builtin_amdgcn_sched_barrier(0);
  __builtin_amdgcn_s_barrier();                      // all waves' A visible

  // trackers: 16 row-slots (m*4+r), top-2 as packed u32 keys (monotone f32|col)
  unsigned t0[16], t1[16];
#pragma unroll
  for (int s = 0; s < 16; s++) { t0[s] = 0xFFFFFFFFu; t1[s] = 0xFFFFFFFFu; }

  f32x4 accA[4][4], accB[4][4];
  float enC0 = 0.f, enC1 = 0.f, enC2 = 0.f, enC3 = 0.f;   // current phase en
  float enP0 = 0.f, enP1 = 0.f, enP2 = 0.f, enP3 = 0.f;   // previous phase en

  auto runphase = [&](f32x4 (&ACC)[4][4], f32x4 (&PRV)[4][4],
                      int ntbase, int pnt, bool dp) {
#pragma unroll
    for (int m = 0; m < 4; m++)
#pragma unroll
      for (int n = 0; n < 4; n++) ACC[m][n] = (f32x4){0.f, 0.f, 0.f, 0.f};

#pragma unroll
    for (int kk = 0; kk < 8; kk++) {
      const int t = ntbase*8 + kk;
      if (t) {                                   // single barrier: slot reuse
        asm volatile("s_waitcnt lgkmcnt(0)" ::: "memory");
        __builtin_amdgcn_sched_barrier(0);
        __builtin_amdgcn_s_barrier();
      }
      if (t < 63) stageB(t + 1);
      // exact wait for OWN stage(t): newer = st(t+1):4 (+ en:4 iff kk==1)
      if (t == 63)      asm volatile("s_waitcnt vmcnt(0)" ::: "memory");
      else if (kk == 1) asm volatile("s_waitcnt vmcnt(8)" ::: "memory");
      else              asm volatile("s_waitcnt vmcnt(4)" ::: "memory");
      __builtin_amdgcn_sched_barrier(0);

      if (kk == 0) {                             // rotate en regs; prefetch this
        enP0 = enC0; enP1 = enC1; enP2 = enC2; enP3 = enC3;  // phase's en (used
        enC0 = enormf[n0 + ntbase*128 + (wc*4 + 0)*16 + l15];// next phase)
        enC1 = enormf[n0 + ntbase*128 + (wc*4 + 1)*16 + l15];
        enC2 = enormf[n0 + ntbase*128 + (wc*4 + 2)*16 + l15];
        enC3 = enormf[n0 + ntbase*128 + (wc*4 + 3)*16 + l15];
      }

      bf16x8 af[4], bfr[4];
#pragma unroll
      for (int m = 0; m < 4; m++)
        af[m] = *(const bf16x8*)&Ash[kk*8 + wr*4 + m][lane*8];
#pragma unroll
      for (int n = 0; n < 4; n++)
        bfr[n] = *(const bf16x8*)&Bsh[t & 1][wc*4 + n][lane*8];
      __builtin_amdgcn_s_setprio(1);
#pragma unroll
      for (int m = 0; m < 4; m++)
#pragma unroll
        for (int n = 0; n < 4; n++)
          ACC[m][n] = __builtin_amdgcn_mfma_f32_16x16x32_bf16(af[m], bfr[n], ACC[m][n], 0, 0, 0);
      __builtin_amdgcn_s_setprio(0);

      if (dp) {                                  // deferred epilogue slice (8 vals)
        const int n = kk >> 1, hf = kk & 1;
        const float pen = (n == 0) ? enP0 : (n == 1) ? enP1 : (n == 2) ? enP2 : enP3;
        const int pcol = n0 + pnt*128 + (wc*4 + n)*16 + l15;
#pragma unroll
        for (int mm = 0; mm < 2; mm++) {
          const int m = hf*2 + mm;
#pragma unroll
          for (int r = 0; r < 4; r++) {
            const float cv = fmaf(-2.f, PRV[m][n][r], pen);
            unsigned u = __float_as_uint(cv);
            unsigned key = u ^ ((unsigned)((int)u >> 31) | 0x80000000u);
            key = (key & 0xFFFFF800u) | (unsigned)pcol;
            const int s = m*4 + r;
            unsigned mx = key > t0[s] ? key : t0[s];
            t0[s] = key < t0[s] ? key : t0[s];
            t1[s] = mx < t1[s] ? mx : t1[s];
          }
        }
      }
    }
  };

  for (int nt = 0; nt < 8; nt += 2) {
    runphase(accA, accB, nt,     nt - 1, nt > 0);
    runphase(accB, accA, nt + 1, nt,     true);
  }
  // tail: process accB of nt=7 (en of nt=7 is in enC)
#pragma unroll
  for (int kk = 0; kk < 8; kk++) {
    const int n = kk >> 1, hf = kk & 1;
    const float pen = (n == 0) ? enC0 : (n == 1) ? enC1 : (n == 2) ? enC2 : enC3;
    const int pcol = n0 + 7*128 + (wc*4 + n)*16 + l15;
#pragma unroll
    for (int mm = 0; mm < 2; mm++) {
      const int m = hf*2 + mm;
#pragma unroll
      for (int r = 0; r < 4; r++) {
        const float cv = fmaf(-2.f, accB[m][n][r], pen);
        unsigned u = __float_as_uint(cv);
        unsigned key = u ^ ((unsigned)((int)u >> 31) | 0x80000000u);
        key = (key & 0xFFFFF800u) | (unsigned)pcol;
        const int s = m*4 + r;
        unsigned mx = key > t0[s] ? key : t0[s];
        t0[s] = key < t0[s] ? key : t0[s];
        t1[s] = mx < t1[s] ? mx : t1[s];
      }
    }
  }

  // ---- merge 32 trackers x top-2 -> top-4 per row (stride 65: no conflicts) ----
  __syncthreads();
  unsigned* KeyM = (unsigned*)&Ash[0][0];      // [128 rows][65] = 33.3 KB
  const int tk = wc*16 + l15;
#pragma unroll
  for (int s = 0; s < 16; s++) {
    const int r = wr*64 + (s >> 2)*16 + l4*4 + (s & 3);
    KeyM[r*65 + tk*2 + 0] = t0[s];
    KeyM[r*65 + tk*2 + 1] = t1[s];
  }
  __syncthreads();
  if (tid < 128) {
    unsigned bk[4];
#pragma unroll
    for (int j = 0; j < 4; j++) bk[j] = 0xFFFFFFFFu;
    for (int e = 0; e < 64; e++) {
      unsigned v = KeyM[tid*65 + e];
      if (v < bk[3]) {
        int j = 3;
        while (j > 0 && v < bk[j-1]) { bk[j] = bk[j-1]; j--; }
        bk[j] = v;
      }
    }
    int* cr = cand + ((size_t)(row0 + tid)) * NC + nhalf*4;
#pragma unroll
    for (int j = 0; j < 4; j++) cr[j] = (int)(bk[j] & 2047u);
  }
}

// ---------------------------------------------------------------------------
// K6 (rescore): wave per row, 4 rows/block, grid 8192. Full 8-cand f64
// rescore + min (tie -> smaller k), then the wave writes the zq row directly.
// ---------------------------------------------------------------------------
__global__ __launch_bounds__(256) void k6_rescore(
    const float* __restrict__ zE, const float* __restrict__ emb,
    const double* __restrict__ enorm, const int* __restrict__ cand,
    float* __restrict__ zq) {
  const int wv = threadIdx.x >> 6, lane = threadIdx.x & 63;
  const size_t row = (size_t)blockIdx.x * 4 + wv;
  const int j = lane >> 3, q = lane & 7;
  const int k = cand[row * NC + j];
  const float* er = emb + ((size_t)k << 8);
  const float* zr = zE + (row << 8);
  double a0 = 0.0, a1 = 0.0, a2 = 0.0, a3 = 0.0;
#pragma unroll
  for (int it = 0; it < 8; it++) {
    const int e0 = it*32 + q*4;
    const float4 ev = *(const float4*)(er + e0);
    const float4 zv = *(const float4*)(zr + e0);
    a0 = fma((double)ev.x, (double)zv.x, a0);
    a1 = fma((double)ev.y, (double)zv.y, a1);
    a2 = fma((double)ev.z, (double)zv.z, a2);
    a3 = fma((double)ev.w, (double)zv.w, a3);
  }
  double dot = (a0 + a1) + (a2 + a3);
  dot += __shfl_xor(dot, 1, 64);
  dot += __shfl_xor(dot, 2, 64);
  dot += __shfl_xor(dot, 4, 64);
  double cv = enorm[k] - 2.0 * dot;
  int bk = k;
#pragma unroll
  for (int off = 8; off < 64; off <<= 1) {       // full 8-cand min reduce
    double ocv = __shfl_xor(cv, off, 64);
    int    okk = __shfl_xor(bk, off, 64);
    if (ocv < cv || (ocv == cv && okk < bk)) { cv = ocv; bk = okk; }
  }
  const float4 ew = *(const float4*)(emb + ((size_t)bk << 8) + lane*4);
  *(float4*)(zq + (row << 8) + lane*4) = ew;
}

// ---------------------------------------------------------------------------
// K7 (decode): block per (b,h). Pure decode: read zq rows (no dependent
// gather), decoder conv + tanh -> x_tilde.
// ---------------------------------------------------------------------------
__global__ __launch_bounds__(256) void k7_decode(
    const float* __restrict__ zq, const float* __restrict__ wdec,
    float* __restrict__ xt) {
  __shared__ __attribute__((aligned(16))) float zs[C][272];    // 17 KB
  __shared__ __attribute__((aligned(16))) float part[4][256];  // 4 KB
  __shared__ float wt[C*T];
  const int bh = blockIdx.x, b = bh >> 6, h = bh & 63;
  const int tid = threadIdx.x;

  if (tid < C*T) {
    int c = tid / T, t = tid % T;
    wt[c*T + t] = wdec[c*T + (T-1-t)];
  }
  for (int i2 = tid; i2 < C*D; i2 += 256) {
    int c = i2 >> 8, dd = i2 & 255;
    zs[c][dd + PAD] = zq[((((size_t)b*C + c)*H + h) << 8) + dd];
  }
  { int jj = tid & 15, c = tid >> 4;
    int pos = (jj < 7) ? jj : (256 + PAD + (jj - 7));
    zs[c][pos] = 0.f; }
  __syncthreads();

  const int dg = tid & 63, cg = tid >> 6;
  float f[20];
  float oo[4] = {0.f, 0.f, 0.f, 0.f};
#pragma unroll
  for (int ci = 0; ci < 4; ci++) {
    const int c = cg*4 + ci;
#pragma unroll
    for (int kq = 0; kq < 5; kq++)
      *(float4*)&f[kq*4] = *(const float4*)&zs[c][dg*4 + kq*4];
#pragma unroll
    for (int jj = 0; jj < 4; jj++)
#pragma unroll
      for (int t = 0; t < T; t++)
        oo[jj] = fmaf(wt[c*T + t], f[jj + t], oo[jj]);
  }
  *(float4*)&part[cg][dg*4] = make_float4(oo[0], oo[1], oo[2], oo[3]);
  __syncthreads();
  float r = part[0][tid] + part[1][tid] + part[2][tid] + part[3][tid];
  xt[((size_t)bh << 8) + tid] = tanhf(r);
}

// ---------------------------------------------------------------------------
extern "C" void kernel_launch(void* const* d_in, const int* in_sizes, int n_in,
                              void* d_out, int out_size, void* d_ws, size_t ws_size,
                              hipStream_t stream) {
  const float* x     = (const float*)d_in[0];
  const float* w_enc = (const float*)d_in[1];
  const float* gamma = (const float*)d_in[2];
  const float* beta  = (const float*)d_in[3];
  const float* emb   = (const float*)d_in[4];
  const float* w_dec = (const float*)d_in[5];

  float* out = (float*)d_out;
  float* xt = out;                                    // 524288
  float* zE = out + (size_t)B*H*D;                    // 8388608 (z_e f32)
  float* zq = out + (size_t)B*H*D + (size_t)B*C*H*D;  // 8388608

  char* ws = (char*)d_ws;
  double* partial = (double*)(ws);                       // 524288 B
  double* params  = (double*)(ws + 524288);              // 512 B
  double* enorm   = (double*)(ws + 524800);              // 16384 B
  float*  enormf  = (float*) (ws + 541184);              // 8192 B
  int*    cand    = (int*)   (ws + 549376);              // 32768*8*4 = 1 MiB
  __hip_bfloat16* zEb  = (__hip_bfloat16*)(ws + 1597952);   // 16 MiB
  __hip_bfloat16* embB = (__hip_bfloat16*)(ws + 18375168);  // 1 MiB

  k0_fused<<<BH + 512, 256, 0, stream>>>(x, w_enc, partial, emb, enorm, enormf, embB);
  k2_stats_final<<<C, 256, 0, stream>>>(partial, gamma, beta, params);
  k1b_ze<<<BH, 256, 0, stream>>>(x, w_enc, params, zE, zEb);
  k4_mfma<<<512, 256, 0, stream>>>(zEb, embB, enormf, cand);
  k6_rescore<<<ROWS/4, 256, 0, stream>>>(zE, emb, enorm, cand, zq);
  k7_decode<<<BH, 256, 0, stream>>>(zq, w_dec, xt);
}

// Round 18
// 131.071 us; speedup vs baseline: 1.2702x; 1.2702x over previous
//
#include <hip/hip_runtime.h>
#include <hip/hip_bf16.h>
#include <cstddef>
#include <cstdint>

// Problem constants
#define B   32
#define C   16
#define H   64
#define D   256
#define K   2048
#define T   15
#define PAD 7
#define EPS 1e-5

#define BH      (B*H)       // 2048
#define ROWS    (B*C*H)     // 32768 VQ rows
#define N_PER_CH ((double)(B*H*D)) // 524288
#define NC  8               // candidates per row (4 per N-half)

typedef __attribute__((ext_vector_type(8))) short bf16x8;
typedef __attribute__((ext_vector_type(4))) float f32x4;

__device__ __forceinline__ void gload_lds16(const void* g, void* l) {
  __builtin_amdgcn_global_load_lds(
      (const __attribute__((address_space(1))) unsigned int*)g,
      (__attribute__((address_space(3))) unsigned int*)l, 16, 0, 0);
}

// ---------------------------------------------------------------------------
// K0 (fused): blocks [0,BH): stats-only encoder conv (f64) partial sums
//             (transposed partial layout [c][bh] for coalesced k2 reads).
//             blocks [BH, BH+512): emb prep — enorm f64 (+f32) + bf16 cast.
// ---------------------------------------------------------------------------
__global__ __launch_bounds__(256) void k0_fused(
    const float* __restrict__ x, const float* __restrict__ w,
    double* __restrict__ partial /* [C][BH][2] */,
    const float* __restrict__ emb, double* __restrict__ enorm,
    float* __restrict__ enormf, __hip_bfloat16* __restrict__ embB) {
  __shared__ __attribute__((aligned(16))) float xs[272];
  __shared__ float wsm[C*T];
  const int bh = blockIdx.x, tid = threadIdx.x;
  if (bh >= BH) {
    const int k = (bh - BH) * 4 + (tid >> 6);
    const int lane = tid & 63;
    const float4 ev = *(const float4*)(emb + ((size_t)k << 8) + lane*4);
    __hip_bfloat16 hb[4] = {__float2bfloat16(ev.x), __float2bfloat16(ev.y),
                            __float2bfloat16(ev.z), __float2bfloat16(ev.w)};
    *(int2*)(embB + ((size_t)k << 8) + lane*4) = *(const int2*)hb;
    double s = fma((double)ev.x, (double)ev.x,
               fma((double)ev.y, (double)ev.y,
               fma((double)ev.z, (double)ev.z,
                   (double)ev.w * (double)ev.w)));
#pragma unroll
    for (int off = 1; off < 64; off <<= 1) s += __shfl_xor(s, off, 64);
    if (lane == 0) { enorm[k] = s; enormf[k] = (float)s; }
    return;
  }
  const float* xrow = x + ((size_t)bh << 8);
  if (tid < C*T) wsm[tid] = w[tid];
  xs[tid] = (tid >= 7 && tid < 263) ? xrow[tid - 7] : 0.f;
  if (tid < 16) { int i = 256 + tid; xs[i] = (i < 263) ? xrow[i - 7] : 0.f; }
  __syncthreads();
  const int c = tid >> 4, s = tid & 15;
  float xr[32];
#pragma unroll
  for (int kq = 0; kq < 8; kq++)
    *(float4*)&xr[kq*4] = *(const float4*)&xs[s*16 + kq*4];
  float wv[T];
#pragma unroll
  for (int t = 0; t < T; t++) wv[t] = wsm[c*T + t];
  double sum = 0.0, sq = 0.0;
#pragma unroll
  for (int d0 = 0; d0 < 16; d0++) {
    double z = 0.0;
#pragma unroll
    for (int t = 0; t < T; t++) z = fma((double)wv[t], (double)xr[d0 + t], z);
    sum += z; sq = fma(z, z, sq);
  }
#pragma unroll
  for (int off = 1; off < 16; off <<= 1) {
    sum += __shfl_xor(sum, off, 64);
    sq  += __shfl_xor(sq,  off, 64);
  }
  if (s == 0) {
    partial[((size_t)c*BH + bh)*2 + 0] = sum;
    partial[((size_t)c*BH + bh)*2 + 1] = sq;
  }
}

// ---------------------------------------------------------------------------
// K2: finalize BN per-channel params (deterministic tree, coalesced reads)
// ---------------------------------------------------------------------------
__global__ __launch_bounds__(256) void k2_stats_final(
    const double* __restrict__ partial, const float* __restrict__ gamma,
    const float* __restrict__ beta, double* __restrict__ params) {
  __shared__ double rs[256], rq[256];
  const int c = blockIdx.x;
  const int tid = threadIdx.x;
  double s = 0.0, q = 0.0;
  for (int i = tid; i < BH; i += 256) {
    s += partial[((size_t)c*BH + i)*2 + 0];
    q += partial[((size_t)c*BH + i)*2 + 1];
  }
  rs[tid] = s; rq[tid] = q;
  __syncthreads();
  for (int off = 128; off; off >>= 1) {
    if (tid < off) { rs[tid] += rs[tid + off]; rq[tid] += rq[tid + off]; }
    __syncthreads();
  }
  if (tid == 0) {
    double m = rs[0] / N_PER_CH;
    double v = rq[0] / N_PER_CH - m * m;
    double a = (double)gamma[c] / sqrt(v + EPS);
    double b = (double)beta[c] - a * m;
    params[c*4+0] = m; params[c*4+1] = v; params[c*4+2] = a; params[c*4+3] = b;
  }
}

// ---------------------------------------------------------------------------
// K1b: encoder conv (f64) + fused affine -> z_e f32 (output) + z_e bf16 (k4 A)
// ---------------------------------------------------------------------------
__global__ __launch_bounds__(256) void k1b_ze(
    const float* __restrict__ x, const float* __restrict__ w,
    const double* __restrict__ params, float* __restrict__ zE,
    __hip_bfloat16* __restrict__ zEb) {
  __shared__ __attribute__((aligned(16))) float xs[272];
  __shared__ float wsm[C*T];
  const int bh = blockIdx.x, tid = threadIdx.x;
  const int b = bh >> 6, h = bh & 63;
  const float* xrow = x + ((size_t)bh << 8);
  if (tid < C*T) wsm[tid] = w[tid];
  xs[tid] = (tid >= 7 && tid < 263) ? xrow[tid - 7] : 0.f;
  if (tid < 16) { int i = 256 + tid; xs[i] = (i < 263) ? xrow[i - 7] : 0.f; }
  __syncthreads();
  const int c = tid >> 4, s = tid & 15;
  float xr[32];
#pragma unroll
  for (int kq = 0; kq < 8; kq++)
    *(float4*)&xr[kq*4] = *(const float4*)&xs[s*16 + kq*4];
  float wv[T];
#pragma unroll
  for (int t = 0; t < T; t++) wv[t] = wsm[c*T + t];
  const double a = params[c*4+2], bb = params[c*4+3];
  float zf[16];
  __hip_bfloat16 zb[16];
#pragma unroll
  for (int d0 = 0; d0 < 16; d0++) {
    double z = 0.0;
#pragma unroll
    for (int t = 0; t < T; t++) z = fma((double)wv[t], (double)xr[d0 + t], z);
    double ze = fma(a, z, bb);
    zf[d0] = (float)ze;
    zb[d0] = __float2bfloat16(zf[d0]);
  }
  const size_t rbase = ((((size_t)b*C + c)*H + h) << 8) + s*16;
#pragma unroll
  for (int kq = 0; kq < 4; kq++)
    *(float4*)(zE + rbase + kq*4) = *(const float4*)&zf[kq*4];
  *(int4*)(zEb + rbase)     = *(const int4*)&zb[0];
  *(int4*)(zEb + rbase + 8) = *(const int4*)&zb[8];
}

// ---------------------------------------------------------------------------
// K4: round-13's measured-best kernel (68.1 us), byte-identical.
// Writes cand = top-4 per N-half (NC=8 per row).
// ---------------------------------------------------------------------------
__global__ __launch_bounds__(256, 2) void k4_mfma(
    const __hip_bfloat16* __restrict__ zEb, const __hip_bfloat16* __restrict__ embB,
    const float* __restrict__ enormf, int* __restrict__ cand /*[ROWS][NC]*/) {
  __shared__ __attribute__((aligned(16))) __hip_bfloat16 Ash[64][512];   // 64 KB
  __shared__ __attribute__((aligned(16))) __hip_bfloat16 Bsh[2][8][512]; // 16 KB

  const int tid  = threadIdx.x;
  const int w    = tid >> 6, lane = tid & 63;
  const int wr   = w >> 1,   wc   = w & 1;
  const int l15  = lane & 15, l4  = lane >> 4;
  const int mblk = blockIdx.x >> 1, nhalf = blockIdx.x & 1;
  const int row0 = mblk * 128;
  const int n0   = nhalf * 1024;

  // ---- prologue: A slab (64 frags) + B step 0 ----
#pragma unroll
  for (int i = 0; i < 16; i++) {
    int f = w*16 + i;
    int kk = f >> 3, mf = f & 7;
    gload_lds16(zEb + (((size_t)(row0 + mf*16 + l15)) << 8) + kk*32 + l4*8,
                &Ash[kk*8 + mf][0]);
  }
  auto stageB = [&](int t) {
    const int slot = t & 1, nt = t >> 3, kk = t & 7;
#pragma unroll
    for (int j = 0; j < 2; j++) {
      int nf = w*2 + j;
      gload_lds16(embB + (((size_t)(n0 + nt*128 + nf*16 + l15)) << 8) + kk*32 + l4*8,
                  &Bsh[slot][nf][0]);
    }
  };
  stageB(0);
  asm volatile("s_waitcnt vmcnt(0) lgkmcnt(0)" ::: "memory");
  __builtin_amdgcn_sched_barrier(0);
  __builtin_amdgcn_s_barrier();

  // trackers: 16 row-slots (m*4+r), top-2 as packed u32 keys (monotone f32|col)
  unsigned t0[16], t1[16];
#pragma unroll
  for (int s = 0; s < 16; s++) { t0[s] = 0xFFFFFFFFu; t1[s] = 0xFFFFFFFFu; }

  f32x4 accA[4][4], accB[4][4];
  float enC0 = 0.f, enC1 = 0.f, enC2 = 0.f, enC3 = 0.f;   // current phase en
  float enP0 = 0.f, enP1 = 0.f, enP2 = 0.f, enP3 = 0.f;   // previous phase en

  auto runphase = [&](f32x4 (&ACC)[4][4], f32x4 (&PRV)[4][4],
                      int ntbase, int pnt, bool dp) {
#pragma unroll
    for (int m = 0; m < 4; m++)
#pragma unroll
      for (int n = 0; n < 4; n++) ACC[m][n] = (f32x4){0.f, 0.f, 0.f, 0.f};

#pragma unroll
    for (int kk = 0; kk < 8; kk++) {
      const int t = ntbase*8 + kk;
      if (t) __builtin_amdgcn_s_barrier();       // barrier_A: prev reads consumed
      if (t < 63) {
        stageB(t + 1);
        if (kk == 1) asm volatile("s_waitcnt vmcnt(6)" ::: "memory");
        else         asm volatile("s_waitcnt vmcnt(2)" ::: "memory");
      } else {
        asm volatile("s_waitcnt vmcnt(0)" ::: "memory");
      }
      __builtin_amdgcn_sched_barrier(0);
      __builtin_amdgcn_s_barrier();              // barrier_B: stage(t) visible

      if (kk == 0) {                             // rotate en regs; prefetch this
        enP0 = enC0; enP1 = enC1; enP2 = enC2; enP3 = enC3;  // phase's en (used
        enC0 = enormf[n0 + ntbase*128 + (wc*4 + 0)*16 + l15];// next phase)
        enC1 = enormf[n0 + ntbase*128 + (wc*4 + 1)*16 + l15];
        enC2 = enormf[n0 + ntbase*128 + (wc*4 + 2)*16 + l15];
        enC3 = enormf[n0 + ntbase*128 + (wc*4 + 3)*16 + l15];
      }

      bf16x8 af[4], bfr[4];
#pragma unroll
      for (int m = 0; m < 4; m++)
        af[m] = *(const bf16x8*)&Ash[kk*8 + wr*4 + m][lane*8];
#pragma unroll
      for (int n = 0; n < 4; n++)
        bfr[n] = *(const bf16x8*)&Bsh[t & 1][wc*4 + n][lane*8];
#pragma unroll
      for (int m = 0; m < 4; m++)
#pragma unroll
        for (int n = 0; n < 4; n++)
          ACC[m][n] = __builtin_amdgcn_mfma_f32_16x16x32_bf16(af[m], bfr[n], ACC[m][n], 0, 0, 0);

      if (dp) {                                  // deferred epilogue slice (8 vals)
        const int n = kk >> 1, hf = kk & 1;
        const float pen = (n == 0) ? enP0 : (n == 1) ? enP1 : (n == 2) ? enP2 : enP3;
        const int pcol = n0 + pnt*128 + (wc*4 + n)*16 + l15;
#pragma unroll
        for (int mm = 0; mm < 2; mm++) {
          const int m = hf*2 + mm;
#pragma unroll
          for (int r = 0; r < 4; r++) {
            const float cv = fmaf(-2.f, PRV[m][n][r], pen);
            unsigned u = __float_as_uint(cv);
            unsigned key = u ^ ((unsigned)((int)u >> 31) | 0x80000000u);
            key = (key & 0xFFFFF800u) | (unsigned)pcol;
            const int s = m*4 + r;
            unsigned mx = key > t0[s] ? key : t0[s];
            t0[s] = key < t0[s] ? key : t0[s];
            t1[s] = mx < t1[s] ? mx : t1[s];
          }
        }
      }
    }
  };

  for (int nt = 0; nt < 8; nt += 2) {
    runphase(accA, accB, nt,     nt - 1, nt > 0);
    runphase(accB, accA, nt + 1, nt,     true);
  }
  // tail: process accB of nt=7 (en of nt=7 is in enC)
#pragma unroll
  for (int kk = 0; kk < 8; kk++) {
    const int n = kk >> 1, hf = kk & 1;
    const float pen = (n == 0) ? enC0 : (n == 1) ? enC1 : (n == 2) ? enC2 : enC3;
    const int pcol = n0 + 7*128 + (wc*4 + n)*16 + l15;
#pragma unroll
    for (int mm = 0; mm < 2; mm++) {
      const int m = hf*2 + mm;
#pragma unroll
      for (int r = 0; r < 4; r++) {
        const float cv = fmaf(-2.f, accB[m][n][r], pen);
        unsigned u = __float_as_uint(cv);
        unsigned key = u ^ ((unsigned)((int)u >> 31) | 0x80000000u);
        key = (key & 0xFFFFF800u) | (unsigned)pcol;
        const int s = m*4 + r;
        unsigned mx = key > t0[s] ? key : t0[s];
        t0[s] = key < t0[s] ? key : t0[s];
        t1[s] = mx < t1[s] ? mx : t1[s];
      }
    }
  }

  // ---- merge 32 trackers x top-2 -> top-4 per row (stride 65: no conflicts) ----
  __syncthreads();
  unsigned* KeyM = (unsigned*)&Ash[0][0];      // [128 rows][65] = 33.3 KB
  const int tk = wc*16 + l15;
#pragma unroll
  for (int s = 0; s < 16; s++) {
    const int r = wr*64 + (s >> 2)*16 + l4*4 + (s & 3);
    KeyM[r*65 + tk*2 + 0] = t0[s];
    KeyM[r*65 + tk*2 + 1] = t1[s];
  }
  __syncthreads();
  if (tid < 128) {
    unsigned bk[4];
#pragma unroll
    for (int j = 0; j < 4; j++) bk[j] = 0xFFFFFFFFu;
    for (int e = 0; e < 64; e++) {
      unsigned v = KeyM[tid*65 + e];
      if (v < bk[3]) {
        int j = 3;
        while (j > 0 && v < bk[j-1]) { bk[j] = bk[j-1]; j--; }
        bk[j] = v;
      }
    }
    int* cr = cand + ((size_t)(row0 + tid)) * NC + nhalf*4;
#pragma unroll
    for (int j = 0; j < 4; j++) cr[j] = (int)(bk[j] & 2047u);
  }
}

// ---------------------------------------------------------------------------
// K6 (rescore): wave per row, 4 rows/block, grid 8192. Lane = (cand j, chunk q):
// 8 lanes/cand read 128-B contiguous segments; all cands share zE addresses
// (L1 broadcast). f64 dot -> 3-step shfl reduce -> per-half min -> rscV/rscK.
// ---------------------------------------------------------------------------
__global__ __launch_bounds__(256) void k6_rescore(
    const float* __restrict__ zE, const float* __restrict__ emb,
    const double* __restrict__ enorm, const int* __restrict__ cand,
    double* __restrict__ rscV, int* __restrict__ rscK) {
  const int wv = threadIdx.x >> 6, lane = threadIdx.x & 63;
  const size_t row = (size_t)blockIdx.x * 4 + wv;
  const int j = lane >> 3, q = lane & 7;
  const int k = cand[row * NC + j];
  const float* er = emb + ((size_t)k << 8);
  const float* zr = zE + (row << 8);
  double a0 = 0.0, a1 = 0.0, a2 = 0.0, a3 = 0.0;
#pragma unroll
  for (int it = 0; it < 8; it++) {
    const int e0 = it*32 + q*4;
    const float4 ev = *(const float4*)(er + e0);
    const float4 zv = *(const float4*)(zr + e0);
    a0 = fma((double)ev.x, (double)zv.x, a0);
    a1 = fma((double)ev.y, (double)zv.y, a1);
    a2 = fma((double)ev.z, (double)zv.z, a2);
    a3 = fma((double)ev.w, (double)zv.w, a3);
  }
  double dot = (a0 + a1) + (a2 + a3);
  dot += __shfl_xor(dot, 1, 64);
  dot += __shfl_xor(dot, 2, 64);
  dot += __shfl_xor(dot, 4, 64);
  double cv = enorm[k] - 2.0 * dot;
  int bk = k;
#pragma unroll
  for (int off = 8; off < 32; off <<= 1) {       // reduce across 4 cands per half
    double ocv = __shfl_xor(cv, off, 64);
    int    okk = __shfl_xor(bk, off, 64);
    if (ocv < cv || (ocv == cv && okk < bk)) { cv = ocv; bk = okk; }
  }
  if ((lane & 31) == 0) {
    rscV[row*2 + (lane >> 5)] = cv;
    rscK[row*2 + (lane >> 5)] = bk;
  }
}

// ---------------------------------------------------------------------------
// K7 (decode): block per (b,h). Pick per-row winner across the 2 halves
// (exact f64, tie -> smaller k), gather emb -> z_q, decoder conv + tanh.
// ---------------------------------------------------------------------------
__global__ __launch_bounds__(256) void k7_decode(
    const float* __restrict__ emb, const double* __restrict__ rscV,
    const int* __restrict__ rscK, const float* __restrict__ wdec,
    float* __restrict__ zq, float* __restrict__ xt) {
  __shared__ __attribute__((aligned(16))) float zs[C][272];    // 17 KB
  __shared__ __attribute__((aligned(16))) float part[4][256];  // 4 KB
  __shared__ float wt[C*T];
  __shared__ int bkS[C];
  const int bh = blockIdx.x, b = bh >> 6, h = bh & 63;
  const int tid = threadIdx.x;

  if (tid < C) {
    const size_t rid = ((size_t)b*C + tid)*H + h;
    const double cv0 = rscV[rid*2 + 0], cv1 = rscV[rid*2 + 1];
    const int    k0  = rscK[rid*2 + 0], k1  = rscK[rid*2 + 1];
    bkS[tid] = (cv1 < cv0 || (cv1 == cv0 && k1 < k0)) ? k1 : k0;
  }
  if (tid < C*T) {
    int c = tid / T, t = tid % T;
    wt[c*T + t] = wdec[c*T + (T-1-t)];
  }
  __syncthreads();

  for (int i2 = tid; i2 < C*D; i2 += 256) {
    int c = i2 >> 8, dd = i2 & 255;
    float v = emb[((size_t)bkS[c] << 8) + dd];
    zs[c][dd + PAD] = v;
    zq[((((size_t)b*C + c)*H + h) << 8) + dd] = v;
  }
  { int jj = tid & 15, c = tid >> 4;
    int pos = (jj < 7) ? jj : (256 + PAD + (jj - 7));
    zs[c][pos] = 0.f; }
  __syncthreads();

  const int dg = tid & 63, cg = tid >> 6;
  float f[20];
  float oo[4] = {0.f, 0.f, 0.f, 0.f};
#pragma unroll
  for (int ci = 0; ci < 4; ci++) {
    const int c = cg*4 + ci;
#pragma unroll
    for (int kq = 0; kq < 5; kq++)
      *(float4*)&f[kq*4] = *(const float4*)&zs[c][dg*4 + kq*4];
#pragma unroll
    for (int jj = 0; jj < 4; jj++)
#pragma unroll
      for (int t = 0; t < T; t++)
        oo[jj] = fmaf(wt[c*T + t], f[jj + t], oo[jj]);
  }
  *(float4*)&part[cg][dg*4] = make_float4(oo[0], oo[1], oo[2], oo[3]);
  __syncthreads();
  float r = part[0][tid] + part[1][tid] + part[2][tid] + part[3][tid];
  xt[((size_t)bh << 8) + tid] = tanhf(r);
}

// ---------------------------------------------------------------------------
extern "C" void kernel_launch(void* const* d_in, const int* in_sizes, int n_in,
                              void* d_out, int out_size, void* d_ws, size_t ws_size,
                              hipStream_t stream) {
  const float* x     = (const float*)d_in[0];
  const float* w_enc = (const float*)d_in[1];
  const float* gamma = (const float*)d_in[2];
  const float* beta  = (const float*)d_in[3];
  const float* emb   = (const float*)d_in[4];
  const float* w_dec = (const float*)d_in[5];

  float* out = (float*)d_out;
  float* xt = out;                                    // 524288
  float* zE = out + (size_t)B*H*D;                    // 8388608 (z_e f32)
  float* zq = out + (size_t)B*H*D + (size_t)B*C*H*D;  // 8388608

  char* ws = (char*)d_ws;
  double* partial = (double*)(ws);                       // 524288 B
  double* params  = (double*)(ws + 524288);              // 512 B
  double* enorm   = (double*)(ws + 524800);              // 16384 B
  float*  enormf  = (float*) (ws + 541184);              // 8192 B
  int*    cand    = (int*)   (ws + 549376);              // 32768*8*4 = 1 MiB
  double* rscV    = (double*)(ws + 1597952);             // 524288 B
  int*    rscK    = (int*)   (ws + 2122240);             // 262144 B
  __hip_bfloat16* zEb  = (__hip_bfloat16*)(ws + 2384384);   // 16 MiB
  __hip_bfloat16* embB = (__hip_bfloat16*)(ws + 19161600);  // 1 MiB

  k0_fused<<<BH + 512, 256, 0, stream>>>(x, w_enc, partial, emb, enorm, enormf, embB);
  k2_stats_final<<<C, 256, 0, stream>>>(partial, gamma, beta, params);
  k1b_ze<<<BH, 256, 0, stream>>>(x, w_enc, params, zE, zEb);
  k4_mfma<<<512, 256, 0, stream>>>(zEb, embB, enormf, cand);
  k6_rescore<<<ROWS/4, 256, 0, stream>>>(zE, emb, enorm, cand, rscV, rscK);
  k7_decode<<<BH, 256, 0, stream>>>(emb, rscV, rscK, w_dec, zq, xt);
}